// Round 15
// baseline (187.931 us; speedup 1.0000x reference)
//
#include <hip/hip_runtime.h>

#define Q 8                // index-stripes per person (sample partition; grid = n*Q blocks)
#define NR 8               // register-held verts per thread (covers V <= 8192)

// ---------------------------------------------------------------------------
// R27: ABLATION PROBE on R25 (best, 23.7 us). The OPTIMIZED raster phase is
// executed TWICE (R23's proven method): atomicMin is idempotent, so grid and
// output are bit-identical to R25 (absmax 0.0); the wall delta measures the
// post-R24/R25 raster cost in situ. Everything else byte-identical to R25.
// ---------------------------------------------------------------------------
__global__ __launch_bounds__(1024) void k_fused(const float* __restrict__ verts,
                                                const float* __restrict__ trans,
                                                float* __restrict__ part,
                                                int V, int n,
                                                const int* __restrict__ pP) {
    __shared__ int   grid[32 * 1024];      // full 32^3 d^2 bits, 128 KB
    __shared__ float red[16][6];
    __shared__ float c4s[4];
    __shared__ float racc[16];

    int bq  = blockIdx.x;
    int p   = bq / Q;
    int q   = bq - p * Q;
    int tid = threadIdx.x, lane = tid & 63, wave = tid >> 6;

    // init full grid: 8192 int4 stores, 8 per thread, conflict-free
    {
        int4* g4 = (int4*)grid;
        int4  fill = make_int4(0x7F7F7F7F, 0x7F7F7F7F, 0x7F7F7F7F, 0x7F7F7F7F);
        #pragma unroll
        for (int k = 0; k < 8; ++k) g4[tid + (k << 10)] = fill;
    }

    const float* vp = verts + (size_t)p * V * 3;

    // --- 1. load own verts into registers + bounds (identical to R25) -----
    float rx[NR], ry[NR], rz[NR];
    {
        float mnx = 3.4e38f, mny = 3.4e38f, mnz = 3.4e38f;
        float mxx = -3.4e38f, mxy = -3.4e38f, mxz = -3.4e38f;
        #pragma unroll
        for (int r = 0; r < NR; ++r) {
            int j = tid + (r << 10);
            if (j < V) {
                float x = vp[3 * j + 0], y = vp[3 * j + 1], z = vp[3 * j + 2];
                rx[r] = x; ry[r] = y; rz[r] = z;
                mnx = fminf(mnx, x); mxx = fmaxf(mxx, x);
                mny = fminf(mny, y); mxy = fmaxf(mxy, y);
                mnz = fminf(mnz, z); mxz = fmaxf(mxz, z);
            } else {
                rx[r] = 0.0f; ry[r] = 0.0f; rz[r] = 0.0f;
            }
        }
        // streamed tail (only if V > NR*1024; never taken for V=6890)
        for (int j = tid + (NR << 10); j < V; j += 1024) {
            float x = vp[3 * j + 0], y = vp[3 * j + 1], z = vp[3 * j + 2];
            mnx = fminf(mnx, x); mxx = fmaxf(mxx, x);
            mny = fminf(mny, y); mxy = fmaxf(mxy, y);
            mnz = fminf(mnz, z); mxz = fmaxf(mxz, z);
        }
        for (int m = 32; m > 0; m >>= 1) {
            mnx = fminf(mnx, __shfl_xor(mnx, m)); mxx = fmaxf(mxx, __shfl_xor(mxx, m));
            mny = fminf(mny, __shfl_xor(mny, m)); mxy = fmaxf(mxy, __shfl_xor(mxy, m));
            mnz = fminf(mnz, __shfl_xor(mnz, m)); mxz = fmaxf(mxz, __shfl_xor(mxz, m));
        }
        if (lane == 0) {
            red[wave][0] = mnx; red[wave][1] = mny; red[wave][2] = mnz;
            red[wave][3] = mxx; red[wave][4] = mxy; red[wave][5] = mxz;
        }
        __syncthreads();
        if (tid == 0) {
            float a0 = red[0][0], a1 = red[0][1], a2 = red[0][2];
            float b0 = red[0][3], b1 = red[0][4], b2 = red[0][5];
            for (int w = 1; w < 16; ++w) {
                a0 = fminf(a0, red[w][0]); a1 = fminf(a1, red[w][1]); a2 = fminf(a2, red[w][2]);
                b0 = fmaxf(b0, red[w][3]); b1 = fmaxf(b1, red[w][4]); b2 = fmaxf(b2, red[w][5]);
            }
            float tx = trans[p * 3 + 0], ty = trans[p * 3 + 1], tz = trans[p * 3 + 2];
            float scale = 0.6f * fmaxf(b0 - a0, fmaxf(b1 - a1, b2 - a2));  // (1+0.2)*0.5
            c4s[0] = 0.5f * (a0 + b0) + tx;
            c4s[1] = 0.5f * (a1 + b1) + ty;
            c4s[2] = 0.5f * (a2 + b2) + tz;
            c4s[3] = scale;
        }
        __syncthreads();
    }
    float cx = c4s[0], cy = c4s[1], cz = c4s[2], s = c4s[3];
    float inv = 1.0f / s;
    float tx = trans[p * 3 + 0], ty = trans[p * 3 + 1], tz = trans[p * 3 + 2];
    float rg = (4.65f * inv) * 1.0005f + 0.005f;
    const float step = 2.0f / 31.0f;

    // --- 2. raster x2 (idempotent): wave-uniform 3x3x3, hoisted terms -----
    for (int rep = 0; rep < 2; ++rep) {
        #pragma unroll
        for (int r = 0; r < NR; ++r) {
            int j = tid + (r << 10);
            if (j < V) {
                float wx = rx[r] + tx;
                float wy = ry[r] + ty;
                float wz = rz[r] + tz;
                float gvx = ((wx - cx) * inv + 1.0f) * 15.5f;
                float gvy = ((wy - cy) * inv + 1.0f) * 15.5f;
                float gvz = ((wz - cz) * inv + 1.0f) * 15.5f;
                int x0 = max(0, (int)ceilf(gvx - rg)), x1 = min(31, (int)floorf(gvx + rg));
                int y0 = max(0, (int)ceilf(gvy - rg)), y1 = min(31, (int)floorf(gvy + rg));
                int z0 = max(0, (int)ceilf(gvz - rg)), z1 = min(31, (int)floorf(gvz + rg));
                bool small = (x1 - x0 < 3) && (y1 - y0 < 3) && (z1 - z0 < 3);
                if (small) {
                    float dx2v[3], dyv[3], dzv[3];
                    #pragma unroll
                    for (int i = 0; i < 3; ++i) {
                        float qx = fmaf((float)(x0 + i), step, -1.0f) * s + cx;
                        float dx = qx - wx;
                        dx2v[i] = dx * dx;
                    }
                    #pragma unroll
                    for (int jj = 0; jj < 3; ++jj) {
                        float qy = fmaf((float)(y0 + jj), step, -1.0f) * s + cy;
                        dyv[jj] = qy - wy;
                    }
                    #pragma unroll
                    for (int k = 0; k < 3; ++k) {
                        float qz = fmaf((float)(z0 + k), step, -1.0f) * s + cz;
                        dzv[k] = qz - wz;
                    }
                    int b0 = (x0 << 10) | (y0 << 5) | z0;
                    #pragma unroll
                    for (int i = 0; i < 3; ++i) {
                        bool vx = (x0 + i <= x1);
                        #pragma unroll
                        for (int jj = 0; jj < 3; ++jj) {
                            float dxy = fmaf(dyv[jj], dyv[jj], dx2v[i]);
                            bool vxy = vx && (y0 + jj <= y1);
                            #pragma unroll
                            for (int k = 0; k < 3; ++k) {
                                float d2 = fmaf(dzv[k], dzv[k], dxy);
                                if (vxy && (z0 + k <= z1) && (d2 < 0.09f))
                                    atomicMin(&grid[b0 + (i << 10) + (jj << 5) + k],
                                              __float_as_int(d2));
                            }
                        }
                    }
                } else {
                    // fallback (span > 3): never taken for this data
                    for (int xi = x0; xi <= x1; ++xi) {
                        float qx = fmaf((float)xi, step, -1.0f) * s + cx;
                        float dx = qx - wx;
                        float dx2 = dx * dx;
                        if (dx2 >= 0.09f) continue;
                        for (int yi = y0; yi <= y1; ++yi) {
                            float qy = fmaf((float)yi, step, -1.0f) * s + cy;
                            float dy = qy - wy;
                            float dxy = fmaf(dy, dy, dx2);
                            if (dxy >= 0.09f) continue;
                            for (int zi = z0; zi <= z1; ++zi) {
                                float qz = fmaf((float)zi, step, -1.0f) * s + cz;
                                float dz = qz - wz;
                                float d2 = fmaf(dz, dz, dxy);
                                if (d2 < 0.09f)
                                    atomicMin(&grid[(xi << 10) | (yi << 5) | zi],
                                              __float_as_int(d2));
                            }
                        }
                    }
                }
            }
        }
        // streamed tail (V > NR*1024 only): raster directly from global
        for (int j = tid + (NR << 10); j < V; j += 1024) {
            float wx = vp[3 * j + 0] + tx;
            float wy = vp[3 * j + 1] + ty;
            float wz = vp[3 * j + 2] + tz;
            float gvx = ((wx - cx) * inv + 1.0f) * 15.5f;
            float gvy = ((wy - cy) * inv + 1.0f) * 15.5f;
            float gvz = ((wz - cz) * inv + 1.0f) * 15.5f;
            int x0 = max(0, (int)ceilf(gvx - rg)), x1 = min(31, (int)floorf(gvx + rg));
            int y0 = max(0, (int)ceilf(gvy - rg)), y1 = min(31, (int)floorf(gvy + rg));
            int z0 = max(0, (int)ceilf(gvz - rg)), z1 = min(31, (int)floorf(gvz + rg));
            for (int xi = x0; xi <= x1; ++xi) {
                float qx = fmaf((float)xi, step, -1.0f) * s + cx;
                float dx = qx - wx;
                float dx2 = dx * dx;
                if (dx2 >= 0.09f) continue;
                for (int yi = y0; yi <= y1; ++yi) {
                    float qy = fmaf((float)yi, step, -1.0f) * s + cy;
                    float dy = qy - wy;
                    float dxy = fmaf(dy, dy, dx2);
                    if (dxy >= 0.09f) continue;
                    for (int zi = z0; zi <= z1; ++zi) {
                        float qz = fmaf((float)zi, step, -1.0f) * s + cz;
                        float dz = qz - wz;
                        float d2 = fmaf(dz, dz, dxy);
                        if (d2 < 0.09f)
                            atomicMin(&grid[(xi << 10) | (yi << 5) | zi],
                                      __float_as_int(d2));
                    }
                }
            }
        }
    }
    __syncthreads();

    // --- 3. sample: index-stripe of each other person, gate-free ----------
    int P = *pP;
    int f = p / P, iloc = p - f * P;
    int jlo = (q * V) / Q, jhi = ((q + 1) * V) / Q;
    float acc = 0.0f;
    for (int jp = 0; jp < P; ++jp) {
        if (jp == iloc) continue;
        int pj = f * P + jp;
        const float* vj = verts + (size_t)pj * V * 3;
        float tjx = trans[pj * 3 + 0], tjy = trans[pj * 3 + 1], tjz = trans[pj * 3 + 2];
        for (int v = jlo + tid; v < jhi; v += 1024) {
            float wx = vj[3 * v + 0] + tjx;
            float wy = vj[3 * v + 1] + tjy;
            float wz = vj[3 * v + 2] + tjz;
            float gx = fminf(fmaxf(((wx - cx) / s + 1.0f) * 15.5f, 0.0f), 31.0f);
            float gy = fminf(fmaxf(((wy - cy) / s + 1.0f) * 15.5f, 0.0f), 31.0f);
            float gz = fminf(fmaxf(((wz - cz) / s + 1.0f) * 15.5f, 0.0f), 31.0f);
            int x0 = min((int)gx, 30);
            int y0 = min((int)gy, 30);
            int z0 = min((int)gz, 30);
            float fx = gx - (float)x0;
            float fy = gy - (float)y0;
            float fz = gz - (float)z0;
            int b = (x0 << 10) | (y0 << 5) | z0;
            float c000 = fmaxf(0.3f - sqrtf(__int_as_float(grid[b])), 0.0f);
            float c100 = fmaxf(0.3f - sqrtf(__int_as_float(grid[b + 1024])), 0.0f);
            float c010 = fmaxf(0.3f - sqrtf(__int_as_float(grid[b + 32])), 0.0f);
            float c110 = fmaxf(0.3f - sqrtf(__int_as_float(grid[b + 1056])), 0.0f);
            float c001 = fmaxf(0.3f - sqrtf(__int_as_float(grid[b + 1])), 0.0f);
            float c101 = fmaxf(0.3f - sqrtf(__int_as_float(grid[b + 1025])), 0.0f);
            float c011 = fmaxf(0.3f - sqrtf(__int_as_float(grid[b + 33])), 0.0f);
            float c111 = fmaxf(0.3f - sqrtf(__int_as_float(grid[b + 1057])), 0.0f);
            float c00 = c000 * (1.0f - fx) + c100 * fx;
            float c10 = c010 * (1.0f - fx) + c110 * fx;
            float c01 = c001 * (1.0f - fx) + c101 * fx;
            float c11 = c011 * (1.0f - fx) + c111 * fx;
            float c0 = c00 * (1.0f - fy) + c10 * fy;
            float c1 = c01 * (1.0f - fy) + c11 * fy;
            float sv = c0 * (1.0f - fz) + c1 * fz;
            acc += fmaxf(sv, 0.0f);
        }
    }
    for (int m = 32; m > 0; m >>= 1) acc += __shfl_xor(acc, m);
    if (lane == 0) racc[wave] = acc;
    __syncthreads();
    if (tid == 0) {
        float t = 0.0f;
        for (int w = 0; w < 16; ++w) t += racc[w];
        part[bq] = t;                       // unconditional -> no zero-init
    }
}

// ---------------------------------------------------------------------------
// Final: parallel weighted reduction (R12-proven, unchanged).
// ---------------------------------------------------------------------------
__global__ __launch_bounds__(256) void k_final(const float* __restrict__ part,
                                               const int* __restrict__ valid,
                                               const int* __restrict__ pP,
                                               float* __restrict__ out, int n) {
    __shared__ float snum[4], sden[4];
    int P = *pP;
    int F = n / P;
    int tot = n * Q;
    int tid = threadIdx.x, lane = tid & 63, wave = tid >> 6;
    float num = 0.0f;
    for (int i = tid; i < tot; i += 256) {
        int f = i / (P * Q);
        num += part[i] * (float)valid[f * P];
    }
    float den = 0.0f;
    for (int f = tid; f < F; f += 256) den += (float)valid[f * P];
    for (int m = 32; m > 0; m >>= 1) {
        num += __shfl_xor(num, m);
        den += __shfl_xor(den, m);
    }
    if (lane == 0) { snum[wave] = num; sden[wave] = den; }
    __syncthreads();
    if (tid == 0) {
        float tn = snum[0] + snum[1] + snum[2] + snum[3];
        float td = sden[0] + sden[1] + sden[2] + sden[3];
        out[0] = tn / td * (1000.0f / (float)(P * P));
    }
}

// ---------------------------------------------------------------------------
extern "C" void kernel_launch(void* const* d_in, const int* in_sizes, int n_in,
                              void* d_out, int out_size, void* d_ws, size_t ws_size,
                              hipStream_t stream) {
    const float* verts = (const float*)d_in[0];
    const float* trans = (const float*)d_in[1];
    const int*   valid = (const int*)d_in[2];       // int32 on device (harness)
    const int*   pP    = (const int*)d_in[5];       // num_people (device scalar)

    int n = in_sizes[1] / 3;                        // total persons
    int V = in_sizes[0] / in_sizes[1];              // vertices per person

    float* part = (float*)d_ws;                     // n*Q floats

    k_fused<<<n * Q, 1024, 0, stream>>>(verts, trans, part, V, n, pP);
    k_final<<<1, 256, 0, stream>>>(part, valid, pP, (float*)d_out, n);
}

// Round 16
// 32.251 us; speedup vs baseline: 5.8272x; 5.8272x over previous
//
#include <hip/hip_runtime.h>

#define Q 8                // stripes per person (raster, merge, sample partition)

// workspace layout
//   part     @ 1024                     (n*Q floats)
//   c4g      @ 16384                    (n*4 floats)
//   merged   @ 65536                    (n   * 32768 ints, ~4.2 MB)
//   partials @ 65536 + n*131072         (n*Q * 32768 ints, ~33.6 MB)

// ---------------------------------------------------------------------------
// R28: partial-grid split + coalesced merge. R25 rasterized all V verts in
// every block (8x chip-wide DS redundancy, ~9 us DS-bound). Here block (p,q)
// rasterizes ONLY stripe q into an LDS partial (1 round x 27 DS vs 7x27),
// writes it out coalesced; k_merge min-reduces the 8 partials (pure int4
// streams); k_sample is R25's sample phase verbatim reading the merged grid
// from global (L2-resident, 8 loads/vert -- NOT R22's 64/vert mistake).
// merged[cell] == R25's grid[cell] exactly (min over disjoint subsets, same
// sentinel, int-min == float-min on non-negative bits); c4 exact; sample
// arithmetic/partition/order verbatim R25 -> absmax 0.0.
// ---------------------------------------------------------------------------

// --- k_raster: bounds + stripe raster into LDS partial, write out ----------
__global__ __launch_bounds__(1024) void k_raster(const float* __restrict__ verts,
                                                 const float* __restrict__ trans,
                                                 float* __restrict__ c4g,
                                                 int* __restrict__ partials,
                                                 int V, int n) {
    __shared__ int   grid[32 * 1024];      // full 32^3 partial, 128 KB
    __shared__ float red[16][6];
    __shared__ float c4s[4];

    int bq  = blockIdx.x;
    int p   = bq / Q;
    int q   = bq - p * Q;
    int tid = threadIdx.x, lane = tid & 63, wave = tid >> 6;

    {
        int4* g4 = (int4*)grid;
        int4  fill = make_int4(0x7F7F7F7F, 0x7F7F7F7F, 0x7F7F7F7F, 0x7F7F7F7F);
        #pragma unroll
        for (int k = 0; k < 8; ++k) g4[tid + (k << 10)] = fill;
    }

    const float* vp = verts + (size_t)p * V * 3;

    // --- 1. bounds scan (exact fmin/fmax -> order-free, c4 bit-identical) -
    {
        float mnx = 3.4e38f, mny = 3.4e38f, mnz = 3.4e38f;
        float mxx = -3.4e38f, mxy = -3.4e38f, mxz = -3.4e38f;
        for (int j = tid; j < V; j += 1024) {
            float x = vp[3 * j + 0], y = vp[3 * j + 1], z = vp[3 * j + 2];
            mnx = fminf(mnx, x); mxx = fmaxf(mxx, x);
            mny = fminf(mny, y); mxy = fmaxf(mxy, y);
            mnz = fminf(mnz, z); mxz = fmaxf(mxz, z);
        }
        for (int m = 32; m > 0; m >>= 1) {
            mnx = fminf(mnx, __shfl_xor(mnx, m)); mxx = fmaxf(mxx, __shfl_xor(mxx, m));
            mny = fminf(mny, __shfl_xor(mny, m)); mxy = fmaxf(mxy, __shfl_xor(mxy, m));
            mnz = fminf(mnz, __shfl_xor(mnz, m)); mxz = fmaxf(mxz, __shfl_xor(mxz, m));
        }
        if (lane == 0) {
            red[wave][0] = mnx; red[wave][1] = mny; red[wave][2] = mnz;
            red[wave][3] = mxx; red[wave][4] = mxy; red[wave][5] = mxz;
        }
        __syncthreads();
        if (tid == 0) {
            float a0 = red[0][0], a1 = red[0][1], a2 = red[0][2];
            float b0 = red[0][3], b1 = red[0][4], b2 = red[0][5];
            for (int w = 1; w < 16; ++w) {
                a0 = fminf(a0, red[w][0]); a1 = fminf(a1, red[w][1]); a2 = fminf(a2, red[w][2]);
                b0 = fmaxf(b0, red[w][3]); b1 = fmaxf(b1, red[w][4]); b2 = fmaxf(b2, red[w][5]);
            }
            float tx = trans[p * 3 + 0], ty = trans[p * 3 + 1], tz = trans[p * 3 + 2];
            float scale = 0.6f * fmaxf(b0 - a0, fmaxf(b1 - a1, b2 - a2));  // (1+0.2)*0.5
            c4s[0] = 0.5f * (a0 + b0) + tx;
            c4s[1] = 0.5f * (a1 + b1) + ty;
            c4s[2] = 0.5f * (a2 + b2) + tz;
            c4s[3] = scale;
            if (q == 0) {                  // publish for k_sample
                c4g[4 * p + 0] = c4s[0]; c4g[4 * p + 1] = c4s[1];
                c4g[4 * p + 2] = c4s[2]; c4g[4 * p + 3] = c4s[3];
            }
        }
        __syncthreads();
    }
    float cx = c4s[0], cy = c4s[1], cz = c4s[2], s = c4s[3];
    float inv = 1.0f / s;
    float tx = trans[p * 3 + 0], ty = trans[p * 3 + 1], tz = trans[p * 3 + 2];
    float rg = (4.65f * inv) * 1.0005f + 0.005f;
    const float step = 2.0f / 31.0f;

    // --- 2. stripe raster: wave-uniform 3x3x3, hoisted (R25's code) -------
    int jlo = (q * V) / Q, jhi = ((q + 1) * V) / Q;
    for (int j = jlo + tid; j < jhi; j += 1024) {
        float wx = vp[3 * j + 0] + tx;
        float wy = vp[3 * j + 1] + ty;
        float wz = vp[3 * j + 2] + tz;
        float gvx = ((wx - cx) * inv + 1.0f) * 15.5f;
        float gvy = ((wy - cy) * inv + 1.0f) * 15.5f;
        float gvz = ((wz - cz) * inv + 1.0f) * 15.5f;
        int x0 = max(0, (int)ceilf(gvx - rg)), x1 = min(31, (int)floorf(gvx + rg));
        int y0 = max(0, (int)ceilf(gvy - rg)), y1 = min(31, (int)floorf(gvy + rg));
        int z0 = max(0, (int)ceilf(gvz - rg)), z1 = min(31, (int)floorf(gvz + rg));
        bool small = (x1 - x0 < 3) && (y1 - y0 < 3) && (z1 - z0 < 3);
        if (small) {
            float dx2v[3], dyv[3], dzv[3];
            #pragma unroll
            for (int i = 0; i < 3; ++i) {
                float qx = fmaf((float)(x0 + i), step, -1.0f) * s + cx;
                float dx = qx - wx;
                dx2v[i] = dx * dx;
            }
            #pragma unroll
            for (int jj = 0; jj < 3; ++jj) {
                float qy = fmaf((float)(y0 + jj), step, -1.0f) * s + cy;
                dyv[jj] = qy - wy;
            }
            #pragma unroll
            for (int k = 0; k < 3; ++k) {
                float qz = fmaf((float)(z0 + k), step, -1.0f) * s + cz;
                dzv[k] = qz - wz;
            }
            int b0 = (x0 << 10) | (y0 << 5) | z0;
            #pragma unroll
            for (int i = 0; i < 3; ++i) {
                bool vx = (x0 + i <= x1);
                #pragma unroll
                for (int jj = 0; jj < 3; ++jj) {
                    float dxy = fmaf(dyv[jj], dyv[jj], dx2v[i]);
                    bool vxy = vx && (y0 + jj <= y1);
                    #pragma unroll
                    for (int k = 0; k < 3; ++k) {
                        float d2 = fmaf(dzv[k], dzv[k], dxy);
                        if (vxy && (z0 + k <= z1) && (d2 < 0.09f))
                            atomicMin(&grid[b0 + (i << 10) + (jj << 5) + k],
                                      __float_as_int(d2));
                    }
                }
            }
        } else {
            // fallback (span > 3): never taken for this data
            for (int xi = x0; xi <= x1; ++xi) {
                float qx = fmaf((float)xi, step, -1.0f) * s + cx;
                float dx = qx - wx;
                float dx2 = dx * dx;
                if (dx2 >= 0.09f) continue;
                for (int yi = y0; yi <= y1; ++yi) {
                    float qy = fmaf((float)yi, step, -1.0f) * s + cy;
                    float dy = qy - wy;
                    float dxy = fmaf(dy, dy, dx2);
                    if (dxy >= 0.09f) continue;
                    for (int zi = z0; zi <= z1; ++zi) {
                        float qz = fmaf((float)zi, step, -1.0f) * s + cz;
                        float dz = qz - wz;
                        float d2 = fmaf(dz, dz, dxy);
                        if (d2 < 0.09f)
                            atomicMin(&grid[(xi << 10) | (yi << 5) | zi],
                                      __float_as_int(d2));
                    }
                }
            }
        }
    }
    __syncthreads();

    // --- 3. write partial (coalesced int4, plain stores) -------------------
    {
        int4* dst = (int4*)(partials + (size_t)bq * 32768);
        const int4* g4 = (const int4*)grid;
        #pragma unroll
        for (int k = 0; k < 8; ++k) dst[tid + (k << 10)] = g4[tid + (k << 10)];
    }
}

// --- k_merge: merged[p][stripe q] = min over the 8 partials ----------------
__global__ __launch_bounds__(1024) void k_merge(const int* __restrict__ partials,
                                                int* __restrict__ merged,
                                                int n) {
    int bq  = blockIdx.x;
    int p   = bq / Q;
    int q   = bq - p * Q;
    int tid = threadIdx.x;

    // this block handles 4096 ints = 1024 threads x int4 (exact)
    size_t cell4 = (size_t)(p * 32768 + q * 4096) / 4 + tid;
    const int4* pg = (const int4*)(partials + (size_t)p * Q * 32768);
    size_t off4 = (size_t)(q * 4096) / 4 + tid;

    int4 m = pg[off4];                     // partial 0
    #pragma unroll
    for (int qq = 1; qq < Q; ++qq) {
        int4 v = pg[(size_t)qq * 8192 + off4];
        m.x = min(m.x, v.x); m.y = min(m.y, v.y);
        m.z = min(m.z, v.z); m.w = min(m.w, v.w);
    }
    ((int4*)merged)[cell4] = m;
}

// --- k_sample: R25's sample phase verbatim, grid from global merged --------
__global__ __launch_bounds__(1024) void k_sample(const float* __restrict__ verts,
                                                 const float* __restrict__ trans,
                                                 const float* __restrict__ c4g,
                                                 const int* __restrict__ merged,
                                                 float* __restrict__ part,
                                                 int V, int n,
                                                 const int* __restrict__ pP) {
    __shared__ float racc[16];
    int bq  = blockIdx.x;
    int p   = bq / Q;
    int q   = bq - p * Q;
    int tid = threadIdx.x, lane = tid & 63, wave = tid >> 6;

    float cx = c4g[4 * p + 0], cy = c4g[4 * p + 1];
    float cz = c4g[4 * p + 2], s  = c4g[4 * p + 3];
    const int* gg = merged + (size_t)p * 32768;

    int P = *pP;
    int f = p / P, iloc = p - f * P;
    int jlo = (q * V) / Q, jhi = ((q + 1) * V) / Q;

    float acc = 0.0f;
    for (int jp = 0; jp < P; ++jp) {
        if (jp == iloc) continue;
        int pj = f * P + jp;
        const float* vj = verts + (size_t)pj * V * 3;
        float tjx = trans[pj * 3 + 0], tjy = trans[pj * 3 + 1], tjz = trans[pj * 3 + 2];
        for (int v = jlo + tid; v < jhi; v += 1024) {
            float wx = vj[3 * v + 0] + tjx;
            float wy = vj[3 * v + 1] + tjy;
            float wz = vj[3 * v + 2] + tjz;
            float gx = fminf(fmaxf(((wx - cx) / s + 1.0f) * 15.5f, 0.0f), 31.0f);
            float gy = fminf(fmaxf(((wy - cy) / s + 1.0f) * 15.5f, 0.0f), 31.0f);
            float gz = fminf(fmaxf(((wz - cz) / s + 1.0f) * 15.5f, 0.0f), 31.0f);
            int x0 = min((int)gx, 30);
            int y0 = min((int)gy, 30);
            int z0 = min((int)gz, 30);
            float fx = gx - (float)x0;
            float fy = gy - (float)y0;
            float fz = gz - (float)z0;
            int b = (x0 << 10) | (y0 << 5) | z0;
            float c000 = fmaxf(0.3f - sqrtf(__int_as_float(gg[b])), 0.0f);
            float c100 = fmaxf(0.3f - sqrtf(__int_as_float(gg[b + 1024])), 0.0f);
            float c010 = fmaxf(0.3f - sqrtf(__int_as_float(gg[b + 32])), 0.0f);
            float c110 = fmaxf(0.3f - sqrtf(__int_as_float(gg[b + 1056])), 0.0f);
            float c001 = fmaxf(0.3f - sqrtf(__int_as_float(gg[b + 1])), 0.0f);
            float c101 = fmaxf(0.3f - sqrtf(__int_as_float(gg[b + 1025])), 0.0f);
            float c011 = fmaxf(0.3f - sqrtf(__int_as_float(gg[b + 33])), 0.0f);
            float c111 = fmaxf(0.3f - sqrtf(__int_as_float(gg[b + 1057])), 0.0f);
            float c00 = c000 * (1.0f - fx) + c100 * fx;
            float c10 = c010 * (1.0f - fx) + c110 * fx;
            float c01 = c001 * (1.0f - fx) + c101 * fx;
            float c11 = c011 * (1.0f - fx) + c111 * fx;
            float c0 = c00 * (1.0f - fy) + c10 * fy;
            float c1 = c01 * (1.0f - fy) + c11 * fy;
            float sv = c0 * (1.0f - fz) + c1 * fz;
            acc += fmaxf(sv, 0.0f);
        }
    }
    for (int m = 32; m > 0; m >>= 1) acc += __shfl_xor(acc, m);
    if (lane == 0) racc[wave] = acc;
    __syncthreads();
    if (tid == 0) {
        float t = 0.0f;
        for (int w = 0; w < 16; ++w) t += racc[w];
        part[bq] = t;                       // unconditional -> no zero-init
    }
}

// --- k_final: parallel weighted reduction (R12-proven, unchanged) ----------
__global__ __launch_bounds__(256) void k_final(const float* __restrict__ part,
                                               const int* __restrict__ valid,
                                               const int* __restrict__ pP,
                                               float* __restrict__ out, int n) {
    __shared__ float snum[4], sden[4];
    int P = *pP;
    int F = n / P;
    int tot = n * Q;
    int tid = threadIdx.x, lane = tid & 63, wave = tid >> 6;
    float num = 0.0f;
    for (int i = tid; i < tot; i += 256) {
        int f = i / (P * Q);
        num += part[i] * (float)valid[f * P];
    }
    float den = 0.0f;
    for (int f = tid; f < F; f += 256) den += (float)valid[f * P];
    for (int m = 32; m > 0; m >>= 1) {
        num += __shfl_xor(num, m);
        den += __shfl_xor(den, m);
    }
    if (lane == 0) { snum[wave] = num; sden[wave] = den; }
    __syncthreads();
    if (tid == 0) {
        float tn = snum[0] + snum[1] + snum[2] + snum[3];
        float td = sden[0] + sden[1] + sden[2] + sden[3];
        out[0] = tn / td * (1000.0f / (float)(P * P));
    }
}

// ---------------------------------------------------------------------------
extern "C" void kernel_launch(void* const* d_in, const int* in_sizes, int n_in,
                              void* d_out, int out_size, void* d_ws, size_t ws_size,
                              hipStream_t stream) {
    const float* verts = (const float*)d_in[0];
    const float* trans = (const float*)d_in[1];
    const int*   valid = (const int*)d_in[2];       // int32 on device (harness)
    const int*   pP    = (const int*)d_in[5];       // num_people (device scalar)

    int n = in_sizes[1] / 3;                        // total persons
    int V = in_sizes[0] / in_sizes[1];              // vertices per person

    float* part     = (float*)((char*)d_ws + 1024);
    float* c4g      = (float*)((char*)d_ws + 16384);
    int*   merged   = (int*)((char*)d_ws + 65536);                       // n*128 KB
    int*   partials = (int*)((char*)d_ws + 65536 + (size_t)n * 131072);  // n*Q*128 KB

    k_raster<<<n * Q, 1024, 0, stream>>>(verts, trans, c4g, partials, V, n);
    k_merge <<<n * Q, 1024, 0, stream>>>(partials, merged, n);
    k_sample<<<n * Q, 1024, 0, stream>>>(verts, trans, c4g, merged, part, V, n, pP);
    k_final <<<1, 256, 0, stream>>>(part, valid, pP, (float*)d_out, n);
}

// Round 17
// 23.474 us; speedup vs baseline: 8.0060x; 1.3739x over previous
//
#include <hip/hip_runtime.h>

#define Q 8                // index-stripes per person (sample partition; grid = n*Q blocks)
#define NR 8               // register-held verts per thread (covers V <= 8192)

// ---------------------------------------------------------------------------
// R29 = R25 (best, 23.7 us) with the window-bound computation removed from
// the uniform raster path: `2*rg < 3` (block-uniform scalar) implies span<3
// for every vert, and rg > radius_grid (x1.0005 + 0.005 margin) means any
// voxel outside the true window fails d2<0.09 automatically -- the same
// margin the original loop's skip logic relies on. So the uniform path
// drops x1/y1/z1 (3x floorf+cvt+min) and the per-vert small test; masks are
// only the array-bounds guard (x0+i <= 31). Admission set identical ->
// grid bit-identical -> absmax 0.0. If 2rg >= 3 the whole block takes the
// original divergent fallback (never for this data).
// ---------------------------------------------------------------------------
__global__ __launch_bounds__(1024) void k_fused(const float* __restrict__ verts,
                                                const float* __restrict__ trans,
                                                float* __restrict__ part,
                                                int V, int n,
                                                const int* __restrict__ pP) {
    __shared__ int   grid[32 * 1024];      // full 32^3 d^2 bits, 128 KB
    __shared__ float red[16][6];
    __shared__ float c4s[4];
    __shared__ float racc[16];

    int bq  = blockIdx.x;
    int p   = bq / Q;
    int q   = bq - p * Q;
    int tid = threadIdx.x, lane = tid & 63, wave = tid >> 6;

    // init full grid: 8192 int4 stores, 8 per thread, conflict-free
    {
        int4* g4 = (int4*)grid;
        int4  fill = make_int4(0x7F7F7F7F, 0x7F7F7F7F, 0x7F7F7F7F, 0x7F7F7F7F);
        #pragma unroll
        for (int k = 0; k < 8; ++k) g4[tid + (k << 10)] = fill;
    }

    const float* vp = verts + (size_t)p * V * 3;

    // --- 1. load own verts into registers + bounds (identical to R25) -----
    float rx[NR], ry[NR], rz[NR];
    {
        float mnx = 3.4e38f, mny = 3.4e38f, mnz = 3.4e38f;
        float mxx = -3.4e38f, mxy = -3.4e38f, mxz = -3.4e38f;
        #pragma unroll
        for (int r = 0; r < NR; ++r) {
            int j = tid + (r << 10);
            if (j < V) {
                float x = vp[3 * j + 0], y = vp[3 * j + 1], z = vp[3 * j + 2];
                rx[r] = x; ry[r] = y; rz[r] = z;
                mnx = fminf(mnx, x); mxx = fmaxf(mxx, x);
                mny = fminf(mny, y); mxy = fmaxf(mxy, y);
                mnz = fminf(mnz, z); mxz = fmaxf(mxz, z);
            } else {
                rx[r] = 0.0f; ry[r] = 0.0f; rz[r] = 0.0f;
            }
        }
        // streamed tail (only if V > NR*1024; never taken for V=6890)
        for (int j = tid + (NR << 10); j < V; j += 1024) {
            float x = vp[3 * j + 0], y = vp[3 * j + 1], z = vp[3 * j + 2];
            mnx = fminf(mnx, x); mxx = fmaxf(mxx, x);
            mny = fminf(mny, y); mxy = fmaxf(mxy, y);
            mnz = fminf(mnz, z); mxz = fmaxf(mxz, z);
        }
        for (int m = 32; m > 0; m >>= 1) {
            mnx = fminf(mnx, __shfl_xor(mnx, m)); mxx = fmaxf(mxx, __shfl_xor(mxx, m));
            mny = fminf(mny, __shfl_xor(mny, m)); mxy = fmaxf(mxy, __shfl_xor(mxy, m));
            mnz = fminf(mnz, __shfl_xor(mnz, m)); mxz = fmaxf(mxz, __shfl_xor(mxz, m));
        }
        if (lane == 0) {
            red[wave][0] = mnx; red[wave][1] = mny; red[wave][2] = mnz;
            red[wave][3] = mxx; red[wave][4] = mxy; red[wave][5] = mxz;
        }
        __syncthreads();
        if (tid == 0) {
            float a0 = red[0][0], a1 = red[0][1], a2 = red[0][2];
            float b0 = red[0][3], b1 = red[0][4], b2 = red[0][5];
            for (int w = 1; w < 16; ++w) {
                a0 = fminf(a0, red[w][0]); a1 = fminf(a1, red[w][1]); a2 = fminf(a2, red[w][2]);
                b0 = fmaxf(b0, red[w][3]); b1 = fmaxf(b1, red[w][4]); b2 = fmaxf(b2, red[w][5]);
            }
            float tx = trans[p * 3 + 0], ty = trans[p * 3 + 1], tz = trans[p * 3 + 2];
            float scale = 0.6f * fmaxf(b0 - a0, fmaxf(b1 - a1, b2 - a2));  // (1+0.2)*0.5
            c4s[0] = 0.5f * (a0 + b0) + tx;
            c4s[1] = 0.5f * (a1 + b1) + ty;
            c4s[2] = 0.5f * (a2 + b2) + tz;
            c4s[3] = scale;
        }
        __syncthreads();
    }
    float cx = c4s[0], cy = c4s[1], cz = c4s[2], s = c4s[3];
    float inv = 1.0f / s;
    float tx = trans[p * 3 + 0], ty = trans[p * 3 + 1], tz = trans[p * 3 + 2];
    float rg = (4.65f * inv) * 1.0005f + 0.005f;
    const float step = 2.0f / 31.0f;
    bool uniformOK = (rg + rg) < 3.0f;     // block-uniform: span <= 2 per dim

    // --- 2. raster: wave-uniform 3x3x3, no window-bound math --------------
    #pragma unroll
    for (int r = 0; r < NR; ++r) {
        int j = tid + (r << 10);
        if (j < V) {
            float wx = rx[r] + tx;
            float wy = ry[r] + ty;
            float wz = rz[r] + tz;
            float gvx = ((wx - cx) * inv + 1.0f) * 15.5f;
            float gvy = ((wy - cy) * inv + 1.0f) * 15.5f;
            float gvz = ((wz - cz) * inv + 1.0f) * 15.5f;
            int x0 = max(0, (int)ceilf(gvx - rg));
            int y0 = max(0, (int)ceilf(gvy - rg));
            int z0 = max(0, (int)ceilf(gvz - rg));
            if (uniformOK) {
                // hoisted per-vert terms (identical expressions -> same bits)
                float dx2v[3], dyv[3], dzv[3];
                #pragma unroll
                for (int i = 0; i < 3; ++i) {
                    float qx = fmaf((float)(x0 + i), step, -1.0f) * s + cx;
                    float dx = qx - wx;
                    dx2v[i] = dx * dx;
                }
                #pragma unroll
                for (int jj = 0; jj < 3; ++jj) {
                    float qy = fmaf((float)(y0 + jj), step, -1.0f) * s + cy;
                    dyv[jj] = qy - wy;
                }
                #pragma unroll
                for (int k = 0; k < 3; ++k) {
                    float qz = fmaf((float)(z0 + k), step, -1.0f) * s + cz;
                    dzv[k] = qz - wz;
                }
                int b0 = (x0 << 10) | (y0 << 5) | z0;
                #pragma unroll
                for (int i = 0; i < 3; ++i) {
                    bool vx = (x0 + i <= 31);          // array-bounds guard only
                    #pragma unroll
                    for (int jj = 0; jj < 3; ++jj) {
                        float dxy = fmaf(dyv[jj], dyv[jj], dx2v[i]);
                        bool vxy = vx && (y0 + jj <= 31);
                        #pragma unroll
                        for (int k = 0; k < 3; ++k) {
                            float d2 = fmaf(dzv[k], dzv[k], dxy);
                            if (vxy && (z0 + k <= 31) && (d2 < 0.09f))
                                atomicMin(&grid[b0 + (i << 10) + (jj << 5) + k],
                                          __float_as_int(d2));
                        }
                    }
                }
            } else {
                // fallback (2rg >= 3): original divergent loop; never taken
                // for this data, block-uniformly skipped.
                int x1 = min(31, (int)floorf(gvx + rg));
                int y1 = min(31, (int)floorf(gvy + rg));
                int z1 = min(31, (int)floorf(gvz + rg));
                for (int xi = x0; xi <= x1; ++xi) {
                    float qx = fmaf((float)xi, step, -1.0f) * s + cx;
                    float dx = qx - wx;
                    float dx2 = dx * dx;
                    if (dx2 >= 0.09f) continue;
                    for (int yi = y0; yi <= y1; ++yi) {
                        float qy = fmaf((float)yi, step, -1.0f) * s + cy;
                        float dy = qy - wy;
                        float dxy = fmaf(dy, dy, dx2);
                        if (dxy >= 0.09f) continue;
                        for (int zi = z0; zi <= z1; ++zi) {
                            float qz = fmaf((float)zi, step, -1.0f) * s + cz;
                            float dz = qz - wz;
                            float d2 = fmaf(dz, dz, dxy);
                            if (d2 < 0.09f)
                                atomicMin(&grid[(xi << 10) | (yi << 5) | zi],
                                          __float_as_int(d2));
                        }
                    }
                }
            }
        }
    }
    // streamed tail (V > NR*1024 only): raster directly from global
    for (int j = tid + (NR << 10); j < V; j += 1024) {
        float wx = vp[3 * j + 0] + tx;
        float wy = vp[3 * j + 1] + ty;
        float wz = vp[3 * j + 2] + tz;
        float gvx = ((wx - cx) * inv + 1.0f) * 15.5f;
        float gvy = ((wy - cy) * inv + 1.0f) * 15.5f;
        float gvz = ((wz - cz) * inv + 1.0f) * 15.5f;
        int x0 = max(0, (int)ceilf(gvx - rg)), x1 = min(31, (int)floorf(gvx + rg));
        int y0 = max(0, (int)ceilf(gvy - rg)), y1 = min(31, (int)floorf(gvy + rg));
        int z0 = max(0, (int)ceilf(gvz - rg)), z1 = min(31, (int)floorf(gvz + rg));
        for (int xi = x0; xi <= x1; ++xi) {
            float qx = fmaf((float)xi, step, -1.0f) * s + cx;
            float dx = qx - wx;
            float dx2 = dx * dx;
            if (dx2 >= 0.09f) continue;
            for (int yi = y0; yi <= y1; ++yi) {
                float qy = fmaf((float)yi, step, -1.0f) * s + cy;
                float dy = qy - wy;
                float dxy = fmaf(dy, dy, dx2);
                if (dxy >= 0.09f) continue;
                for (int zi = z0; zi <= z1; ++zi) {
                    float qz = fmaf((float)zi, step, -1.0f) * s + cz;
                    float dz = qz - wz;
                    float d2 = fmaf(dz, dz, dxy);
                    if (d2 < 0.09f)
                        atomicMin(&grid[(xi << 10) | (yi << 5) | zi],
                                  __float_as_int(d2));
                }
            }
        }
    }
    __syncthreads();

    // --- 3. sample: index-stripe of each other person, gate-free ----------
    int P = *pP;
    int f = p / P, iloc = p - f * P;
    int jlo = (q * V) / Q, jhi = ((q + 1) * V) / Q;
    float acc = 0.0f;
    for (int jp = 0; jp < P; ++jp) {
        if (jp == iloc) continue;
        int pj = f * P + jp;
        const float* vj = verts + (size_t)pj * V * 3;
        float tjx = trans[pj * 3 + 0], tjy = trans[pj * 3 + 1], tjz = trans[pj * 3 + 2];
        for (int v = jlo + tid; v < jhi; v += 1024) {
            float wx = vj[3 * v + 0] + tjx;
            float wy = vj[3 * v + 1] + tjy;
            float wz = vj[3 * v + 2] + tjz;
            float gx = fminf(fmaxf(((wx - cx) / s + 1.0f) * 15.5f, 0.0f), 31.0f);
            float gy = fminf(fmaxf(((wy - cy) / s + 1.0f) * 15.5f, 0.0f), 31.0f);
            float gz = fminf(fmaxf(((wz - cz) / s + 1.0f) * 15.5f, 0.0f), 31.0f);
            int x0 = min((int)gx, 30);
            int y0 = min((int)gy, 30);
            int z0 = min((int)gz, 30);
            float fx = gx - (float)x0;
            float fy = gy - (float)y0;
            float fz = gz - (float)z0;
            int b = (x0 << 10) | (y0 << 5) | z0;
            float c000 = fmaxf(0.3f - sqrtf(__int_as_float(grid[b])), 0.0f);
            float c100 = fmaxf(0.3f - sqrtf(__int_as_float(grid[b + 1024])), 0.0f);
            float c010 = fmaxf(0.3f - sqrtf(__int_as_float(grid[b + 32])), 0.0f);
            float c110 = fmaxf(0.3f - sqrtf(__int_as_float(grid[b + 1056])), 0.0f);
            float c001 = fmaxf(0.3f - sqrtf(__int_as_float(grid[b + 1])), 0.0f);
            float c101 = fmaxf(0.3f - sqrtf(__int_as_float(grid[b + 1025])), 0.0f);
            float c011 = fmaxf(0.3f - sqrtf(__int_as_float(grid[b + 33])), 0.0f);
            float c111 = fmaxf(0.3f - sqrtf(__int_as_float(grid[b + 1057])), 0.0f);
            float c00 = c000 * (1.0f - fx) + c100 * fx;
            float c10 = c010 * (1.0f - fx) + c110 * fx;
            float c01 = c001 * (1.0f - fx) + c101 * fx;
            float c11 = c011 * (1.0f - fx) + c111 * fx;
            float c0 = c00 * (1.0f - fy) + c10 * fy;
            float c1 = c01 * (1.0f - fy) + c11 * fy;
            float sv = c0 * (1.0f - fz) + c1 * fz;
            acc += fmaxf(sv, 0.0f);
        }
    }
    for (int m = 32; m > 0; m >>= 1) acc += __shfl_xor(acc, m);
    if (lane == 0) racc[wave] = acc;
    __syncthreads();
    if (tid == 0) {
        float t = 0.0f;
        for (int w = 0; w < 16; ++w) t += racc[w];
        part[bq] = t;                       // unconditional -> no zero-init
    }
}

// ---------------------------------------------------------------------------
// Final: parallel weighted reduction (R12-proven, unchanged).
// ---------------------------------------------------------------------------
__global__ __launch_bounds__(256) void k_final(const float* __restrict__ part,
                                               const int* __restrict__ valid,
                                               const int* __restrict__ pP,
                                               float* __restrict__ out, int n) {
    __shared__ float snum[4], sden[4];
    int P = *pP;
    int F = n / P;
    int tot = n * Q;
    int tid = threadIdx.x, lane = tid & 63, wave = tid >> 6;
    float num = 0.0f;
    for (int i = tid; i < tot; i += 256) {
        int f = i / (P * Q);
        num += part[i] * (float)valid[f * P];
    }
    float den = 0.0f;
    for (int f = tid; f < F; f += 256) den += (float)valid[f * P];
    for (int m = 32; m > 0; m >>= 1) {
        num += __shfl_xor(num, m);
        den += __shfl_xor(den, m);
    }
    if (lane == 0) { snum[wave] = num; sden[wave] = den; }
    __syncthreads();
    if (tid == 0) {
        float tn = snum[0] + snum[1] + snum[2] + snum[3];
        float td = sden[0] + sden[1] + sden[2] + sden[3];
        out[0] = tn / td * (1000.0f / (float)(P * P));
    }
}

// ---------------------------------------------------------------------------
extern "C" void kernel_launch(void* const* d_in, const int* in_sizes, int n_in,
                              void* d_out, int out_size, void* d_ws, size_t ws_size,
                              hipStream_t stream) {
    const float* verts = (const float*)d_in[0];
    const float* trans = (const float*)d_in[1];
    const int*   valid = (const int*)d_in[2];       // int32 on device (harness)
    const int*   pP    = (const int*)d_in[5];       // num_people (device scalar)

    int n = in_sizes[1] / 3;                        // total persons
    int V = in_sizes[0] / in_sizes[1];              // vertices per person

    float* part = (float*)d_ws;                     // n*Q floats

    k_fused<<<n * Q, 1024, 0, stream>>>(verts, trans, part, V, n, pP);
    k_final<<<1, 256, 0, stream>>>(part, valid, pP, (float*)d_out, n);
}